// Round 1
// baseline (64.947 us; speedup 1.0000x reference)
//
#include <hip/hip_runtime.h>
#include <math.h>

// AttnRes: h[b,t,d] = sum_n softmax_n( rsqrt(mean_d V^2 + eps) * dot(q*w, V[n,b,t,:]) ) * V[n,b,t,d]
// Single-pass fused kernel: one 192-thread block per (b,t), all 12 layers in registers.

constexpr int N_LAYERS = 12;
constexpr int D = 768;
constexpr int THREADS = 192;   // D / 4 floats per thread
constexpr float EPS = 1e-6f;

__global__ __launch_bounds__(THREADS)
void attnres_fused_kernel(const float* __restrict__ V,
                          const float* __restrict__ q,
                          const float* __restrict__ w,
                          float* __restrict__ out,
                          int BT)
{
    const int bt   = blockIdx.x;
    if (bt >= BT) return;
    const int tid  = threadIdx.x;
    const int lane = tid & 63;
    const int wave = tid >> 6;          // 0..2

    // q ⊙ w for this thread's 4 columns
    const int d0 = tid * 4;
    float4 q4 = *reinterpret_cast<const float4*>(q + d0);
    float4 w4 = *reinterpret_cast<const float4*>(w + d0);
    float4 qw = make_float4(q4.x * w4.x, q4.y * w4.y, q4.z * w4.z, q4.w * w4.w);

    const size_t stride_n = (size_t)BT * (size_t)D;
    const float* base = V + (size_t)bt * (size_t)D + d0;

    // Load all 12 layer rows for this (b,t) — 48 VGPRs of values, coalesced float4s.
    float4 v[N_LAYERS];
    #pragma unroll
    for (int n = 0; n < N_LAYERS; ++n) {
        v[n] = *reinterpret_cast<const float4*>(base + (size_t)n * stride_n);
    }

    // Per-thread partials: sum of squares, dot with q*w.
    float ss[N_LAYERS], dq[N_LAYERS];
    #pragma unroll
    for (int n = 0; n < N_LAYERS; ++n) {
        float4 x = v[n];
        ss[n] = x.x * x.x + x.y * x.y + x.z * x.z + x.w * x.w;
        dq[n] = qw.x * x.x + qw.y * x.y + qw.z * x.z + qw.w * x.w;
    }

    // Intra-wave butterfly reduction (64 lanes).
    #pragma unroll
    for (int m = 1; m < 64; m <<= 1) {
        #pragma unroll
        for (int n = 0; n < N_LAYERS; ++n) {
            ss[n] += __shfl_xor(ss[n], m, 64);
            dq[n] += __shfl_xor(dq[n], m, 64);
        }
    }

    // Cross-wave combine via LDS. Static register indices only (rule: runtime-
    // indexed register arrays go to scratch), so lane 0 of each wave writes all.
    __shared__ float red[3][2 * N_LAYERS];
    if (lane == 0) {
        #pragma unroll
        for (int n = 0; n < N_LAYERS; ++n) {
            red[wave][n]            = ss[n];
            red[wave][N_LAYERS + n] = dq[n];
        }
    }
    __syncthreads();

    // Every thread redundantly computes the 12-way softmax (cheap, broadcast LDS reads).
    float logits[N_LAYERS];
    float mx = -3.0e38f;
    #pragma unroll
    for (int n = 0; n < N_LAYERS; ++n) {
        float s = red[0][n] + red[1][n] + red[2][n];
        float d = red[0][N_LAYERS + n] + red[1][N_LAYERS + n] + red[2][N_LAYERS + n];
        float inv_rms = rsqrtf(s * (1.0f / (float)D) + EPS);
        logits[n] = d * inv_rms;
        mx = fmaxf(mx, logits[n]);
    }
    float alpha[N_LAYERS];
    float sum = 0.0f;
    #pragma unroll
    for (int n = 0; n < N_LAYERS; ++n) {
        alpha[n] = __expf(logits[n] - mx);
        sum += alpha[n];
    }
    const float inv_sum = 1.0f / sum;

    // Weighted sum over layers from registers.
    float4 h = make_float4(0.f, 0.f, 0.f, 0.f);
    #pragma unroll
    for (int n = 0; n < N_LAYERS; ++n) {
        float a = alpha[n] * inv_sum;
        h.x += a * v[n].x;
        h.y += a * v[n].y;
        h.z += a * v[n].z;
        h.w += a * v[n].w;
    }

    *reinterpret_cast<float4*>(out + (size_t)bt * (size_t)D + d0) = h;
}

extern "C" void kernel_launch(void* const* d_in, const int* in_sizes, int n_in,
                              void* d_out, int out_size, void* d_ws, size_t ws_size,
                              hipStream_t stream)
{
    const float* V = (const float*)d_in[0];   // [N, B, T, D] fp32
    const float* q = (const float*)d_in[1];   // [D] fp32
    const float* w = (const float*)d_in[2];   // [D] fp32
    float* out = (float*)d_out;               // [B, T, D] fp32

    const int BT = out_size / D;              // B*T = 8192

    attnres_fused_kernel<<<dim3(BT), dim3(THREADS), 0, stream>>>(V, q, w, out, BT);
}

// Round 2
// 60.780 us; speedup vs baseline: 1.0686x; 1.0686x over previous
//
#include <hip/hip_runtime.h>
#include <math.h>

// AttnRes: h[b,t,d] = sum_n softmax_n( rsqrt(mean_d V^2 + eps) * dot(q*w, V[n,b,t,:]) ) * V[n,b,t,d]
// One 192-thread block per (b,t); all 12 layers in registers; wave reduction
// via DPP (VALU pipe) instead of ds_swizzle (LDS pipe) to keep LDS off the
// critical path of this memory-bound kernel.

constexpr int N_LAYERS = 12;
constexpr int D = 768;
constexpr int THREADS = 192;   // D / 4 floats per thread
constexpr float EPS = 1e-6f;

// --- DPP wave-64 sum reduction (result broadcast via readlane -> SGPR) ---
template<int CTRL>
__device__ __forceinline__ float dpp_add(float x) {
    int y = __builtin_amdgcn_update_dpp(0, __builtin_bit_cast(int, x),
                                        CTRL, 0xf, 0xf, false);
    return x + __builtin_bit_cast(float, y);
}

__device__ __forceinline__ float wave_sum_uniform(float x) {
    x = dpp_add<0x111>(x);  // row_shr:1
    x = dpp_add<0x112>(x);  // row_shr:2
    x = dpp_add<0x114>(x);  // row_shr:4
    x = dpp_add<0x118>(x);  // row_shr:8  -> lane15 of each row has row sum
    x = dpp_add<0x142>(x);  // row_bcast:15 -> lane31 = rows0+1, lane63 = rows2+3
    x = dpp_add<0x143>(x);  // row_bcast:31 -> lane63 = total
    return __builtin_bit_cast(float,
        __builtin_amdgcn_readlane(__builtin_bit_cast(int, x), 63));
}

__global__ __launch_bounds__(THREADS)
void attnres_fused_kernel(const float* __restrict__ V,
                          const float* __restrict__ q,
                          const float* __restrict__ w,
                          float* __restrict__ out,
                          int BT)
{
    const int bt   = blockIdx.x;
    const int tid  = threadIdx.x;
    const int lane = tid & 63;
    const int wave = tid >> 6;          // 0..2

    // q ⊙ w for this thread's 4 columns
    const int d0 = tid * 4;
    float4 q4 = *reinterpret_cast<const float4*>(q + d0);
    float4 w4 = *reinterpret_cast<const float4*>(w + d0);
    float4 qw = make_float4(q4.x * w4.x, q4.y * w4.y, q4.z * w4.z, q4.w * w4.w);

    const size_t stride_n = (size_t)BT * (size_t)D;
    const float* base = V + (size_t)bt * (size_t)D + d0;

    // Load all 12 layer rows for this (b,t) — 48 VGPRs, coalesced float4s.
    float4 v[N_LAYERS];
    #pragma unroll
    for (int n = 0; n < N_LAYERS; ++n) {
        v[n] = *reinterpret_cast<const float4*>(base + (size_t)n * stride_n);
    }

    // Per-thread partials: sum of squares, dot with q*w.
    float ss[N_LAYERS], dq[N_LAYERS];
    #pragma unroll
    for (int n = 0; n < N_LAYERS; ++n) {
        float4 x = v[n];
        ss[n] = x.x * x.x + x.y * x.y + x.z * x.z + x.w * x.w;
        dq[n] = qw.x * x.x + qw.y * x.y + qw.z * x.z + qw.w * x.w;
    }

    // Wave-level reduction on the VALU pipe (DPP); results are wave-uniform.
    float wred[2 * N_LAYERS];
    #pragma unroll
    for (int n = 0; n < N_LAYERS; ++n) {
        wred[n]            = wave_sum_uniform(ss[n]);
        wred[N_LAYERS + n] = wave_sum_uniform(dq[n]);
    }

    // Cross-wave combine: lane 0 of each wave writes its 24 uniform sums
    // as 6 float4 stores; after the barrier every thread reads all 3 waves'
    // rows (18 broadcast ds_read_b128 per wave).
    __shared__ float red[3][2 * N_LAYERS];   // [wave][ss0..11, dq0..11]
    if (lane == 0) {
        #pragma unroll
        for (int i = 0; i < 6; ++i) {
            *reinterpret_cast<float4*>(&red[wave][i * 4]) =
                make_float4(wred[i * 4 + 0], wred[i * 4 + 1],
                            wred[i * 4 + 2], wred[i * 4 + 3]);
        }
    }
    __syncthreads();

    float tot[2 * N_LAYERS];
    #pragma unroll
    for (int i = 0; i < 6; ++i) {
        float4 a = *reinterpret_cast<const float4*>(&red[0][i * 4]);
        float4 b = *reinterpret_cast<const float4*>(&red[1][i * 4]);
        float4 c = *reinterpret_cast<const float4*>(&red[2][i * 4]);
        tot[i * 4 + 0] = a.x + b.x + c.x;
        tot[i * 4 + 1] = a.y + b.y + c.y;
        tot[i * 4 + 2] = a.z + b.z + c.z;
        tot[i * 4 + 3] = a.w + b.w + c.w;
    }

    // Softmax over the 12 layers (wave-uniform values, cheap VALU).
    float logits[N_LAYERS];
    float mx = -3.0e38f;
    #pragma unroll
    for (int n = 0; n < N_LAYERS; ++n) {
        float inv_rms = rsqrtf(tot[n] * (1.0f / (float)D) + EPS);
        logits[n] = tot[N_LAYERS + n] * inv_rms;
        mx = fmaxf(mx, logits[n]);
    }
    float alpha[N_LAYERS];
    float sum = 0.0f;
    #pragma unroll
    for (int n = 0; n < N_LAYERS; ++n) {
        alpha[n] = __expf(logits[n] - mx);
        sum += alpha[n];
    }
    const float inv_sum = 1.0f / sum;

    // Weighted sum over layers from registers.
    float4 h = make_float4(0.f, 0.f, 0.f, 0.f);
    #pragma unroll
    for (int n = 0; n < N_LAYERS; ++n) {
        float a = alpha[n] * inv_sum;
        h.x += a * v[n].x;
        h.y += a * v[n].y;
        h.z += a * v[n].z;
        h.w += a * v[n].w;
    }

    *reinterpret_cast<float4*>(out + (size_t)bt * (size_t)D + d0) = h;
}

extern "C" void kernel_launch(void* const* d_in, const int* in_sizes, int n_in,
                              void* d_out, int out_size, void* d_ws, size_t ws_size,
                              hipStream_t stream)
{
    const float* V = (const float*)d_in[0];   // [N, B, T, D] fp32
    const float* q = (const float*)d_in[1];   // [D] fp32
    const float* w = (const float*)d_in[2];   // [D] fp32
    float* out = (float*)d_out;               // [B, T, D] fp32

    const int BT = out_size / D;              // B*T = 8192

    attnres_fused_kernel<<<dim3(BT), dim3(THREADS), 0, stream>>>(V, q, w, out, BT);
}